// Round 2
// baseline (305.369 us; speedup 1.0000x reference)
//
#include <hip/hip_runtime.h>
#include <math.h>

#define NPTS 200001

typedef _Float16 f16;
typedef f16 f16x2 __attribute__((ext_vector_type(2)));
typedef f16 f16x8 __attribute__((ext_vector_type(8)));
typedef float f32x16 __attribute__((ext_vector_type(16)));

// ---------------------------------------------------------------------------
// prep: blocks 0..3: fp32 trapz partial sums for SILU_C / SIG_C
//       blocks 4.. : bake weights into MFMA B-fragment order (f16)
// (unchanged — layout documented in earlier rounds)
// ---------------------------------------------------------------------------
__global__ void prep(const float* __restrict__ wss0, const float* __restrict__ wvv0,
                     const float* __restrict__ wss1, const float* __restrict__ wvv1,
                     const float* __restrict__ wsv,  const float* __restrict__ wvs,
                     float* __restrict__ partials,
                     f16* __restrict__ b1, f16* __restrict__ b2)
{
    const int b = blockIdx.x;
    const int t = threadIdx.x;
    if (b < 4) {
        float ls = 0.f, lg = 0.f;
        for (int i = b * 256 + t; i < NPTS; i += 1024) {
            float xv  = -12.0f + 24.0f * ((float)i / 200000.0f);
            float pdf = __expf(-0.5f * xv * xv) * 0.39894228040143267794f;
            float sg  = 1.0f / (1.0f + __expf(-xv));
            float si  = xv * sg;
            float wt  = (i == 0 || i == NPTS - 1) ? 0.5f : 1.0f;
            ls = fmaf(wt * si * si, pdf, ls);
            lg = fmaf(wt * sg * sg, pdf, lg);
        }
        __shared__ float r1[256], r2[256];
        r1[t] = ls; r2[t] = lg;
        __syncthreads();
        for (int st = 128; st > 0; st >>= 1) {
            if (t < st) { r1[t] += r1[t + st]; r2[t] += r2[t + st]; }
            __syncthreads();
        }
        if (t == 0) { partials[b] = r1[0]; partials[4 + b] = r2[0]; }
    } else {
        const int gid = (b - 4) * 256 + t;
        const float CSC  = 0.05590169943749474241f;                       // 1/sqrt(320)
        const float CSC3 = 0.05590169943749474241f / 1.7320508075688772935f;
        if (gid < 14336) {                      // B1: [28][64][8]
            const int e = gid;
            const int tt   = e >> 9;
            const int lane = (e >> 3) & 63;
            const int j    = e & 7;
            const int n    = lane & 31;
            const int hf   = lane >> 5;
            const int k    = tt * 16 + hf * 8 + j;
            float val = 0.f;
            if (k < 256) {
                const int u = k >> 4, t16 = k & 15;
                if (n < 16)      val = CSC * wss0[(u * 16 + t16) * 16 + n];
                else if (n < 24) val = CSC * wss1[(u * 16 + t16) * 8 + (n - 16)];
            } else {
                const int kk = k - 256;
                const int r8 = (kk >> 3) & 7, c8 = kk & 7;
                if (n < 16)      val = CSC3 * wvv0[(r8 * 8 + c8) * 16 + n];
                else if (n < 24) val = CSC3 * wvv1[(r8 * 8 + c8) * 8 + (n - 16)];
            }
            b1[e] = (f16)val;
        } else if (gid < 18432) {               // B2: [8][64][8]
            const int e = gid - 14336;
            const int tt   = e >> 9;
            const int lane = (e >> 3) & 63;
            const int j    = e & 7;
            const int n    = lane & 31;
            const int hf   = lane >> 5;
            const int k    = tt * 16 + hf * 8 + j;
            const int a = k >> 3, bb = k & 7;
            float val = 0.f;
            if (n < 8)
                val = 0.0625f * (wsv[(a * 8 + bb) * 8 + n] + wvs[(bb * 16 + a) * 8 + n]);
            b2[e] = (f16)val;
        }
    }
}

// ---------------------------------------------------------------------------
// Main kernel v3: B-fragments in LDS (v2, validated: 0 bank conflicts) BUT
// no cross-loop prefetch buffer (v2's xr[40] live-across-MFMA + (256,3) cap
// forced a scratch spill -> +320MB scratch traffic, the v2 regression).
// Row load -> immediate convert via NAMED float4 regs (short live range, no
// indexed array). Epilogue fused: gate swizzled per-r, gall[] eliminated.
// __launch_bounds__(256,4): 128-VGPR cap -> 4 waves/SIMD; LDS 36,864B x 4
// blocks = 147KB/CU fits. TLP (16 waves/CU) hides row-load latency.
// C-layout: col = lane&31, row = (reg&3)+8*(reg>>2)+4*(lane>>5).
// ---------------------------------------------------------------------------
__global__ __launch_bounds__(256, 4) void seg_main(
    const float* __restrict__ x,
    const f16* __restrict__ b1,       // [28][64][8]
    const f16* __restrict__ b2,       // [8][64][8]
    const float* __restrict__ partials,
    float* __restrict__ out, int n, int nchunks)
{
    const int lane = threadIdx.x & 63;
    const int wid  = threadIdx.x >> 6;
    const int col  = lane & 31;
    const int hf   = lane >> 5;

    // ---- stage all B fragments into LDS: 28,672 + 8,192 = 36,864 B ----
    __shared__ float4 ldsB[2304];
    {
        const float4* b1v4 = (const float4*)b1;   // 1792 float4
        const float4* b2v4 = (const float4*)b2;   // 512 float4
#pragma unroll
        for (int i = 0; i < 7; ++i) ldsB[i * 256 + threadIdx.x] = b1v4[i * 256 + threadIdx.x];
#pragma unroll
        for (int i = 0; i < 2; ++i) ldsB[1792 + i * 256 + threadIdx.x] = b2v4[i * 256 + threadIdx.x];
    }
    __syncthreads();
    // frag t of B1 at f16x8 index t*64+lane (contiguous 1024B per wave ->
    // conflict-free ds_read_b128); B2 frag t at 1792 + t*64 + lane.
    const f16x8* Bf = (const f16x8*)ldsB;

    const float dx = 24.0f / 200000.0f;
    const float silu_c = rsqrtf((partials[0] + partials[1] + partials[2] + partials[3]) * dx);
    const float sig_c  = rsqrtf((partials[4] + partials[5] + partials[6] + partials[7]) * dx);

    const int stride = gridDim.x * 4;

    for (int chunk = blockIdx.x * 4 + wid; chunk < nchunks; chunk += stride) {
        const int row  = chunk * 32 + col;
        const int lrow = (row < n) ? row : (n - 1);

        // ---- load row as named float4s, convert immediately (short live range)
        f16x2 s2[8];        // s2[a] = {s[2a], s[2a+1]}
        f16x2 vc[3][4];     // vc[i][m] = {v[2m][i], v[2m+1][i]}
        {
            const float4* p4 = (const float4*)(x + (size_t)lrow * 40);
            float4 q0 = p4[0], q1 = p4[1], q2 = p4[2], q3 = p4[3], q4 = p4[4];
            float4 q5 = p4[5], q6 = p4[6], q7 = p4[7], q8 = p4[8], q9 = p4[9];
            s2[0].x = (f16)q0.x; s2[0].y = (f16)q0.y;
            s2[1].x = (f16)q0.z; s2[1].y = (f16)q0.w;
            s2[2].x = (f16)q1.x; s2[2].y = (f16)q1.y;
            s2[3].x = (f16)q1.z; s2[3].y = (f16)q1.w;
            s2[4].x = (f16)q2.x; s2[4].y = (f16)q2.y;
            s2[5].x = (f16)q2.z; s2[5].y = (f16)q2.w;
            s2[6].x = (f16)q3.x; s2[6].y = (f16)q3.y;
            s2[7].x = (f16)q3.z; s2[7].y = (f16)q3.w;
            // vc[i][m] = {xr[16+6m+i], xr[16+6m+3+i]}, xr[16..39] = q4..q9
            vc[0][0].x = (f16)q4.x; vc[0][0].y = (f16)q4.w;
            vc[1][0].x = (f16)q4.y; vc[1][0].y = (f16)q5.x;
            vc[2][0].x = (f16)q4.z; vc[2][0].y = (f16)q5.y;
            vc[0][1].x = (f16)q5.z; vc[0][1].y = (f16)q6.y;
            vc[1][1].x = (f16)q5.w; vc[1][1].y = (f16)q6.z;
            vc[2][1].x = (f16)q6.x; vc[2][1].y = (f16)q6.w;
            vc[0][2].x = (f16)q7.x; vc[0][2].y = (f16)q7.w;
            vc[1][2].x = (f16)q7.y; vc[1][2].y = (f16)q8.x;
            vc[2][2].x = (f16)q7.z; vc[2][2].y = (f16)q8.y;
            vc[0][3].x = (f16)q8.z; vc[0][3].y = (f16)q9.y;
            vc[1][3].x = (f16)q8.w; vc[1][3].y = (f16)q9.z;
            vc[2][3].x = (f16)q9.x; vc[2][3].y = (f16)q9.w;
        }

        // lane's K-half of s: elements hf*8 .. hf*8+7
        f16x2 shp[4];
#pragma unroll
        for (int m = 0; m < 4; ++m) shp[m] = hf ? s2[4 + m] : s2[m];

        union { f16x2 h[4]; f16x8 v; } A;
        f32x16 acc1;
#pragma unroll
        for (int r = 0; r < 16; ++r) acc1[r] = 0.f;

        // ---- path1 ss: ksteps t=0..15, feature_j = s[t] * s[hf*8+j] ----
#pragma unroll
        for (int t = 0; t < 16; ++t) {
            f16 sv = (t & 1) ? s2[t >> 1].y : s2[t >> 1].x;   // compile-time select
            f16x2 su2; su2.x = sv; su2.y = sv;
#pragma unroll
            for (int m = 0; m < 4; ++m) A.h[m] = su2 * shp[m];
            acc1 = __builtin_amdgcn_mfma_f32_32x32x16_f16(A.v, Bf[t * 64 + lane], acc1, 0, 0, 0);
        }
        // ---- path1 vv: ksteps tt=0..11; i = tt>>2, u = 2*(tt&3)+hf ----
#pragma unroll
        for (int tt = 0; tt < 12; ++tt) {
            const int i   = tt >> 2;
            const int ttm = tt & 3;
            f16x2 pr = vc[i][ttm];
            f16 sv = hf ? pr.y : pr.x;
            f16x2 su2; su2.x = sv; su2.y = sv;
#pragma unroll
            for (int m = 0; m < 4; ++m) A.h[m] = su2 * vc[i][m];
            acc1 = __builtin_amdgcn_mfma_f32_32x32x16_f16(A.v, Bf[(16 + tt) * 64 + lane], acc1, 0, 0, 0);
        }

        // ---- fused epilogue path1: silu store + gate swizzle per r ----
        // gate(z, w) lives at col 16+w; consumer lanes (col<8) read lane^16
        // within their 32-lane group -> ds_swizzle BitMode xor=16.
        float gm[16];
#pragma unroll
        for (int r = 0; r < 16; ++r) {
            float val = acc1[r];
            float sgm = 1.0f / (1.0f + __expf(-val));
            const int z  = (r & 3) + 8 * (r >> 2) + 4 * hf;
            const int zr = chunk * 32 + z;
            if (col < 16 && zr < n)
                out[(size_t)zr * 40 + col] = silu_c * val * sgm;
            gm[r] = __int_as_float(
                __builtin_amdgcn_ds_swizzle(__float_as_int(sig_c * sgm), 0x401F));
        }

        // ---- path2: per component i, M-row = z, N-col = w (0..7) ----
#pragma unroll
        for (int i = 0; i < 3; ++i) {
            f32x16 acc2;
#pragma unroll
            for (int r = 0; r < 16; ++r) acc2[r] = 0.f;
#pragma unroll
            for (int t2 = 0; t2 < 8; ++t2) {        // a = 2*t2 + hf
                f16x2 pr = s2[t2];
                f16 sv = hf ? pr.y : pr.x;
                f16x2 su2; su2.x = sv; su2.y = sv;
#pragma unroll
                for (int m = 0; m < 4; ++m) A.h[m] = su2 * vc[i][m];
                acc2 = __builtin_amdgcn_mfma_f32_32x32x16_f16(A.v, Bf[1792 + t2 * 64 + lane], acc2, 0, 0, 0);
            }
            if (col < 8) {
#pragma unroll
                for (int r = 0; r < 16; ++r) {
                    const int z  = (r & 3) + 8 * (r >> 2) + 4 * hf;
                    const int zr = chunk * 32 + z;
                    if (zr < n)
                        out[(size_t)zr * 40 + 16 + col * 3 + i] = gm[r] * acc2[r];
                }
            }
        }
    }
}

// ---------------------------------------------------------------------------
extern "C" void kernel_launch(void* const* d_in, const int* in_sizes, int n_in,
                              void* d_out, int out_size, void* d_ws, size_t ws_size,
                              hipStream_t stream)
{
    (void)n_in; (void)out_size; (void)ws_size;
    const float* x    = (const float*)d_in[0];
    const float* wss0 = (const float*)d_in[1];
    const float* wvv0 = (const float*)d_in[2];
    const float* wss1 = (const float*)d_in[3];
    const float* wvv1 = (const float*)d_in[4];
    const float* wsv  = (const float*)d_in[5];
    const float* wvs  = (const float*)d_in[6];
    float* out = (float*)d_out;
    const int n = in_sizes[0] / 40;
    const int nchunks = (n + 31) / 32;

    char* ws = (char*)d_ws;
    float* partials = (float*)(ws + 0);        // 8 floats
    f16*   b1       = (f16*)(ws + 1024);       // 28*64*8 f16 = 28672 B
    f16*   b2       = (f16*)(ws + 30720);      // 8*64*8 f16  = 8192 B

    int grid = (nchunks + 3) / 4;
    if (grid > 1024) grid = 1024;

    hipLaunchKernelGGL(prep, dim3(76), dim3(256), 0, stream,
                       wss0, wvv0, wss1, wvv1, wsv, wvs, partials, b1, b2);
    hipLaunchKernelGGL(seg_main, dim3(grid), dim3(256), 0, stream,
                       x, b1, b2, partials, out, n, nchunks);
}

// Round 3
// 189.958 us; speedup vs baseline: 1.6076x; 1.6076x over previous
//
#include <hip/hip_runtime.h>
#include <math.h>

#define NPTS 200001

typedef _Float16 f16;
typedef f16 f16x2 __attribute__((ext_vector_type(2)));
typedef f16 f16x8 __attribute__((ext_vector_type(8)));
typedef float f32x16 __attribute__((ext_vector_type(16)));

// ---------------------------------------------------------------------------
// Packed B region (workspace AND LDS image), 24,128 B total:
//   B1: [28 ksteps][49 units][8 f16]  unit = hf*24+col (col<24), unit 48 = zeros
//   B2: [ 8 ksteps][17 units][8 f16]  unit = hf*8+w    (w<8),    unit 16 = zeros
// A lane's B-fragment for a kstep is 16 B at (t*49+unit)*16 (B1) or
// B2OFF+(ks*17+unit)*16 (B2). Out-of-range lanes read the kstep's zero unit
// (same address across those lanes -> LDS broadcast, conflict-free).
// Combined accumulators: accA = path1 (cols 0..15 scal, 16..23 gates) +
// path2 i=0 (cols 24..31); accB = i=1 (cols 0..7) + i=2 (cols 8..15).
// ---------------------------------------------------------------------------
#define B1BYTES  21952
#define B2OFF    21952
#define BBYTES   24128
#define STAGEOFF 24128                  // + wid*2560 : per-wave 16-row staging
#define LDSBYTES (24128 + 4*2560)       // 34,368 B -> 4 blocks/CU

__global__ void prep(const float* __restrict__ wss0, const float* __restrict__ wvv0,
                     const float* __restrict__ wss1, const float* __restrict__ wvv1,
                     const float* __restrict__ wsv,  const float* __restrict__ wvs,
                     float* __restrict__ partials, f16* __restrict__ bpack)
{
    const int b = blockIdx.x;
    const int t = threadIdx.x;
    if (b < 4) {
        float ls = 0.f, lg = 0.f;
        for (int i = b * 256 + t; i < NPTS; i += 1024) {
            float xv  = -12.0f + 24.0f * ((float)i / 200000.0f);
            float pdf = __expf(-0.5f * xv * xv) * 0.39894228040143267794f;
            float sg  = 1.0f / (1.0f + __expf(-xv));
            float si  = xv * sg;
            float wt  = (i == 0 || i == NPTS - 1) ? 0.5f : 1.0f;
            ls = fmaf(wt * si * si, pdf, ls);
            lg = fmaf(wt * sg * sg, pdf, lg);
        }
        __shared__ float r1[256], r2[256];
        r1[t] = ls; r2[t] = lg;
        __syncthreads();
        for (int st = 128; st > 0; st >>= 1) {
            if (t < st) { r1[t] += r1[t + st]; r2[t] += r2[t + st]; }
            __syncthreads();
        }
        if (t == 0) { partials[b] = r1[0]; partials[4 + b] = r2[0]; }
    } else {
        const int gid = (b - 4) * 256 + t;
        const float CSC  = 0.05590169943749474241f;                       // 1/sqrt(320)
        const float CSC3 = 0.05590169943749474241f / 1.7320508075688772935f;
        if (gid < 10976) {                       // B1: [28][49][8]
            const int tk   = gid / 392;          // 49*8
            const int rem  = gid - tk * 392;
            const int unit = rem >> 3;
            const int j    = rem & 7;
            float val = 0.f;
            if (unit < 48) {
                const int hf  = (unit >= 24) ? 1 : 0;
                const int col = unit - 24 * hf;
                const int k   = tk * 16 + hf * 8 + j;
                if (k < 256) {
                    const int u = k >> 4, t16 = k & 15;
                    val = (col < 16) ? CSC * wss0[(u * 16 + t16) * 16 + col]
                                     : CSC * wss1[(u * 16 + t16) * 8 + (col - 16)];
                } else {
                    const int kk = k - 256;
                    const int r8 = (kk >> 3) & 7, c8 = kk & 7;
                    val = (col < 16) ? CSC3 * wvv0[(r8 * 8 + c8) * 16 + col]
                                     : CSC3 * wvv1[(r8 * 8 + c8) * 8 + (col - 16)];
                }
            }
            bpack[gid] = (f16)val;
        } else if (gid < 12064) {                // B2: [8][17][8]
            const int e    = gid - 10976;
            const int ks   = e / 136;            // 17*8
            const int rem  = e - ks * 136;
            const int unit = rem >> 3;
            const int j    = rem & 7;
            float val = 0.f;
            if (unit < 16) {
                const int hf = unit >> 3;
                const int w  = unit & 7;
                const int k  = ks * 16 + hf * 8 + j;
                const int a  = k >> 3, bb = k & 7;
                val = 0.0625f * (wsv[(a * 8 + bb) * 8 + w] + wvs[(bb * 16 + a) * 8 + w]);
            }
            bpack[gid] = (f16)val;
        }
    }
}

// ---------------------------------------------------------------------------
// v4: same math (52 MFMA/chunk, fp32 accum, identical summation order) but
// output goes through per-wave LDS staging and is flushed as 64-lane
// contiguous dwordx4 stores (full 128B lines, one visit per line). This
// removes the partial-sector scattered stores that caused v2/v3's 3x L2
// write/refetch churn at high occupancy. B compressed (zero cols removed)
// so LDS = 34,368 B -> 4 blocks/CU = 16 waves/CU at <=128 regs.
// C-layout: col = lane&31, row = (reg&3)+8*(reg>>2)+4*(lane>>5).
// ---------------------------------------------------------------------------
__global__ __launch_bounds__(256, 4) void seg_main(
    const float* __restrict__ x,
    const f16* __restrict__ bpack,    // 24,128 B packed B1+B2
    const float* __restrict__ partials,
    float* __restrict__ out, int n, int nchunks)
{
    const int tid  = threadIdx.x;
    const int lane = tid & 63;
    const int wid  = tid >> 6;
    const int col  = lane & 31;
    const int hf   = lane >> 5;

    __shared__ float4 lds4[LDSBYTES / 16];
    {
        const float4* src = (const float4*)bpack;
#pragma unroll
        for (int i = 0; i < 6; ++i) {
            const int idx = i * 256 + tid;
            if (idx < BBYTES / 16) lds4[idx] = src[idx];
        }
    }
    __syncthreads();

    char* ldsc = (char*)lds4;
    // per-lane B-fragment base byte offsets (zero unit for inactive lanes)
    const int uA = (col < 24) ? (hf * 24 + col) * 16 : 48 * 16;
    const int u0 = B2OFF + ((col >= 24) ? (hf * 8 + col - 24) * 16 : 256);
    const int u1 = B2OFF + ((col < 8)   ? (hf * 8 + col) * 16      : 256);
    const int u2 = B2OFF + ((col >= 8 && col < 16) ? (hf * 8 + col - 8) * 16 : 256);
    const f16x8* BA  = (const f16x8*)(ldsc + uA);   // index t*49  (784 B stride)
    const f16x8* B0p = (const f16x8*)(ldsc + u0);   // index ks*17 (272 B stride)
    const f16x8* B1p = (const f16x8*)(ldsc + u1);
    const f16x8* B2p = (const f16x8*)(ldsc + u2);

    float*  stagef = (float*)(ldsc + STAGEOFF + wid * 2560);
    float4* stage4 = (float4*)(ldsc + STAGEOFF + wid * 2560);

    // gate(z,w) lives at lane hf*32+16+w; every consumer group uses w = col&7
    const int gsrc = 4 * (hf * 32 + 16 + (col & 7));
    // v-out dword offset within a 40-float row: 16 + w*3 + i per lane group
    const int vo   = 16 + (col & 7) * 3 + ((col < 8) ? 1 : ((col < 16) ? 2 : 0));
    const bool wrV = (col < 16) || (col >= 24);

    const float dx = 24.0f / 200000.0f;
    const float silu_c = rsqrtf((partials[0] + partials[1] + partials[2] + partials[3]) * dx);
    const float sig_c  = rsqrtf((partials[4] + partials[5] + partials[6] + partials[7]) * dx);

    const long long nf40 = (long long)n * 40;
    const int stride = gridDim.x * 4;

    for (int chunk = blockIdx.x * 4 + wid; chunk < nchunks; chunk += stride) {
        const int row  = chunk * 32 + col;
        const int lrow = (row < n) ? row : (n - 1);

        // ---- load row as named float4s, convert immediately ----
        f16x2 s2[8];        // s2[a] = {s[2a], s[2a+1]}
        f16x2 vc[3][4];     // vc[i][m] = {v[2m][i], v[2m+1][i]}
        {
            const float4* p4 = (const float4*)(x + (size_t)lrow * 40);
            float4 q0 = p4[0], q1 = p4[1], q2 = p4[2], q3 = p4[3], q4 = p4[4];
            float4 q5 = p4[5], q6 = p4[6], q7 = p4[7], q8 = p4[8], q9 = p4[9];
            s2[0].x = (f16)q0.x; s2[0].y = (f16)q0.y;
            s2[1].x = (f16)q0.z; s2[1].y = (f16)q0.w;
            s2[2].x = (f16)q1.x; s2[2].y = (f16)q1.y;
            s2[3].x = (f16)q1.z; s2[3].y = (f16)q1.w;
            s2[4].x = (f16)q2.x; s2[4].y = (f16)q2.y;
            s2[5].x = (f16)q2.z; s2[5].y = (f16)q2.w;
            s2[6].x = (f16)q3.x; s2[6].y = (f16)q3.y;
            s2[7].x = (f16)q3.z; s2[7].y = (f16)q3.w;
            vc[0][0].x = (f16)q4.x; vc[0][0].y = (f16)q4.w;
            vc[1][0].x = (f16)q4.y; vc[1][0].y = (f16)q5.x;
            vc[2][0].x = (f16)q4.z; vc[2][0].y = (f16)q5.y;
            vc[0][1].x = (f16)q5.z; vc[0][1].y = (f16)q6.y;
            vc[1][1].x = (f16)q5.w; vc[1][1].y = (f16)q6.z;
            vc[2][1].x = (f16)q6.x; vc[2][1].y = (f16)q6.w;
            vc[0][2].x = (f16)q7.x; vc[0][2].y = (f16)q7.w;
            vc[1][2].x = (f16)q7.y; vc[1][2].y = (f16)q8.x;
            vc[2][2].x = (f16)q7.z; vc[2][2].y = (f16)q8.y;
            vc[0][3].x = (f16)q8.z; vc[0][3].y = (f16)q9.y;
            vc[1][3].x = (f16)q8.w; vc[1][3].y = (f16)q9.z;
            vc[2][3].x = (f16)q9.x; vc[2][3].y = (f16)q9.w;
        }

        f16x2 shp[4];
#pragma unroll
        for (int m = 0; m < 4; ++m) shp[m] = hf ? s2[4 + m] : s2[m];

        union { f16x2 h[4]; f16x8 v; } A;
        f32x16 accA, accB;
#pragma unroll
        for (int r = 0; r < 16; ++r) { accA[r] = 0.f; accB[r] = 0.f; }

        // ---- path1 ss: ksteps t=0..15 -> accA ----
#pragma unroll
        for (int t = 0; t < 16; ++t) {
            f16 sv = (t & 1) ? s2[t >> 1].y : s2[t >> 1].x;
            f16x2 su2; su2.x = sv; su2.y = sv;
#pragma unroll
            for (int m = 0; m < 4; ++m) A.h[m] = su2 * shp[m];
            accA = __builtin_amdgcn_mfma_f32_32x32x16_f16(A.v, BA[t * 49], accA, 0, 0, 0);
        }
        // ---- path1 vv: ksteps tt=0..11 -> accA ----
#pragma unroll
        for (int tt = 0; tt < 12; ++tt) {
            const int i   = tt >> 2;
            const int ttm = tt & 3;
            f16x2 pr = vc[i][ttm];
            f16 sv = hf ? pr.y : pr.x;
            f16x2 su2; su2.x = sv; su2.y = sv;
#pragma unroll
            for (int m = 0; m < 4; ++m) A.h[m] = su2 * vc[i][m];
            accA = __builtin_amdgcn_mfma_f32_32x32x16_f16(A.v, BA[(16 + tt) * 49], accA, 0, 0, 0);
        }
        // ---- path2: i0 -> accA cols 24..31; i1,i2 -> accB cols 0..15 ----
#pragma unroll
        for (int ks = 0; ks < 8; ++ks) {
            f16x2 pr = s2[ks];
            f16 sv = hf ? pr.y : pr.x;
            f16x2 su2; su2.x = sv; su2.y = sv;
            union { f16x2 h[4]; f16x8 v; } A0, A1, A2;
#pragma unroll
            for (int m = 0; m < 4; ++m) {
                A0.h[m] = su2 * vc[0][m];
                A1.h[m] = su2 * vc[1][m];
                A2.h[m] = su2 * vc[2][m];
            }
            accA = __builtin_amdgcn_mfma_f32_32x32x16_f16(A0.v, B0p[ks * 17], accA, 0, 0, 0);
            accB = __builtin_amdgcn_mfma_f32_32x32x16_f16(A1.v, B1p[ks * 17], accB, 0, 0, 0);
            accB = __builtin_amdgcn_mfma_f32_32x32x16_f16(A2.v, B2p[ks * 17], accB, 0, 0, 0);
        }

        // ---- epilogue: stage 16 rows in LDS, flush fully coalesced ----
#pragma unroll
        for (int half = 0; half < 2; ++half) {
#pragma unroll
            for (int rr = 0; rr < 8; ++rr) {
                const int r = half * 8 + rr;
                const float aval = accA[r];
                const float sgm  = 1.0f / (1.0f + __expf(-aval));
                const float gm   = __int_as_float(
                    __builtin_amdgcn_ds_bpermute(gsrc, __float_as_int(sig_c * sgm)));
                const int zloc = (((r & 3) + 8 * (r >> 2)) & 7) + 4 * hf + ((rr >> 2) << 3);
                // zloc = (z - half*16): r<8 -> z in 0..15, r>=8 -> 16..31
                if (col < 16) stagef[zloc * 40 + col] = silu_c * aval * sgm;
                if (wrV)      stagef[zloc * 40 + vo]  = gm * ((col < 16) ? accB[r] : aval);
            }
            // flush 16 rows = 2560 B, contiguous in out
            if ((long long)(chunk * 32 + half * 16 + 15) < (long long)n) {
                float4* o4 = (float4*)out + (size_t)chunk * 320 + half * 160;
                float4 f0 = stage4[lane];
                float4 f1 = stage4[64 + lane];
                o4[lane]      = f0;
                o4[64 + lane] = f1;
                if (lane < 32) { float4 f2 = stage4[128 + lane]; o4[128 + lane] = f2; }
            } else {
#pragma unroll
                for (int k2 = 0; k2 < 3; ++k2) {
                    if (k2 == 2 && lane >= 32) break;
                    float4 fv = stage4[k2 * 64 + lane];
                    const long long fbase = (long long)chunk * 1280 + half * 640
                                          + (k2 * 64 + lane) * 4;
#pragma unroll
                    for (int e = 0; e < 4; ++e) {
                        const long long fi = fbase + e;
                        if (fi < nf40) out[fi] = ((const float*)&fv)[e];
                    }
                }
            }
        }
    }
}

// ---------------------------------------------------------------------------
extern "C" void kernel_launch(void* const* d_in, const int* in_sizes, int n_in,
                              void* d_out, int out_size, void* d_ws, size_t ws_size,
                              hipStream_t stream)
{
    (void)n_in; (void)out_size; (void)ws_size;
    const float* x    = (const float*)d_in[0];
    const float* wss0 = (const float*)d_in[1];
    const float* wvv0 = (const float*)d_in[2];
    const float* wss1 = (const float*)d_in[3];
    const float* wvv1 = (const float*)d_in[4];
    const float* wsv  = (const float*)d_in[5];
    const float* wvs  = (const float*)d_in[6];
    float* out = (float*)d_out;
    const int n = in_sizes[0] / 40;
    const int nchunks = (n + 31) / 32;

    char* ws = (char*)d_ws;
    float* partials = (float*)(ws + 0);        // 8 floats
    f16*   bpack    = (f16*)(ws + 1024);       // 24,128 B packed B1+B2

    int grid = (nchunks + 3) / 4;
    if (grid > 1024) grid = 1024;

    hipLaunchKernelGGL(prep, dim3(52), dim3(256), 0, stream,
                       wss0, wvv0, wss1, wvv1, wsv, wvs, partials, bpack);
    hipLaunchKernelGGL(seg_main, dim3(grid), dim3(256), 0, stream,
                       x, bpack, partials, out, n, nchunks);
}